// Round 7
// baseline (2283.022 us; speedup 1.0000x reference)
//
#include <hip/hip_runtime.h>
#include <math.h>

// Problem constants
#define BB 4
#define NN 192
#define DIN 768
#define HD 256
#define HH 512
#define PP 513         // BIAFF+1
#define CLS 10
#define NBIG 5130      // CLS*PP
#define KP 544         // PP padded to 17*32
#define WCO_LD 1051
#define LMAX 192

typedef __attribute__((ext_vector_type(8))) __bf16 bf16x8;
typedef __attribute__((ext_vector_type(4))) float f32x4;
typedef unsigned short u16;
typedef unsigned int u32;
typedef unsigned long long u64;

__device__ __forceinline__ float sigf(float x) { return 1.f / (1.f + expf(-x)); }

__device__ __forceinline__ u16 f2bf(float f) {
    u32 x = __float_as_uint(f);
    u32 r = (x + 0x7FFF + ((x >> 16) & 1)) >> 16;
    return (u16)r;
}
__device__ __forceinline__ float bf2f(u16 h) {
    return __uint_as_float(((u32)h) << 16);
}

// ---------------------------------------------------------------------------
// mega_prep: all weight/input splits + LSTM weight packing in ONE launch.
// ---------------------------------------------------------------------------
__global__ void mega_prep(const float* __restrict__ word_reps,
                          const float* __restrict__ Wih_f, const float* __restrict__ Wih_b,
                          const float* __restrict__ b_f, const float* __restrict__ b_b,
                          const float* __restrict__ mlp1_w, const float* __restrict__ mlp2_w,
                          const float* __restrict__ head_w, const float* __restrict__ tail_w,
                          const float* __restrict__ mlp1_b, const float* __restrict__ mlp2_b,
                          const float* __restrict__ head_b, const float* __restrict__ tail_b,
                          const float* __restrict__ Whh_f, const float* __restrict__ Whh_b,
                          u16* __restrict__ wrph, u16* __restrict__ wrpl,
                          u16* __restrict__ wihh, u16* __restrict__ wihl, float* __restrict__ bias_ih,
                          u16* __restrict__ mwh, u16* __restrict__ mwl, float* __restrict__ bias_mid,
                          u16* __restrict__ pw)
{
    int i = blockIdx.x * blockDim.x + threadIdx.x;
    if (i < 589824) {
        float v = word_reps[i];
        u16 h = f2bf(v);
        wrph[i] = h; wrpl[i] = f2bf(v - bf2f(h));
        return;
    }
    i -= 589824;
    if (i < 1572864) {
        int n = i / 768, k = i - n * 768;
        float v = (n < 1024) ? Wih_f[(size_t)n * 768 + k] : Wih_b[(size_t)(n - 1024) * 768 + k];
        u16 h = f2bf(v);
        wihh[i] = h; wihl[i] = f2bf(v - bf2f(h));
        return;
    }
    i -= 1572864;
    if (i < 1048576) {
        int n = i >> 9, k = i & 511;
        const float* Ws = (n < 512) ? mlp1_w : (n < 1024) ? mlp2_w : (n < 1536) ? head_w : tail_w;
        float v = Ws[(size_t)(n & 511) * 512 + k];
        u16 h = f2bf(v);
        mwh[i] = h; mwl[i] = f2bf(v - bf2f(h));
        return;
    }
    i -= 1048576;
    if (i < 524288) {
        int f = i;
        int e = f & 7;
        int lane = (f >> 3) & 63;
        int frag = (f >> 9) & 31;
        int wave = (f >> 14) & 7;
        int dh = f >> 17;
        int dir = dh >> 1, half = dh & 1;
        int kt = frag >> 2, t = frag & 3;
        int col = half * 512 + wave * 64 + t * 16 + (lane & 15);
        int u = col >> 2, gt = col & 3;
        int g = gt * 256 + u;
        int k = kt * 32 + (lane >> 4) * 8 + e;
        const float* W = dir ? Whh_b : Whh_f;
        pw[f] = f2bf(W[(size_t)g * 256 + k]);
        return;
    }
    i -= 524288;
    if (i < 2048) {
        bias_ih[i] = (i < 1024) ? b_f[i] : b_b[i - 1024];
        return;
    }
    i -= 2048;
    if (i < 2048) {
        bias_mid[i] = (i < 512) ? mlp1_b[i] : (i < 1024) ? mlp2_b[i - 512]
                    : (i < 1536) ? head_b[i - 1024] : tail_b[i - 1536];
    }
}

// ---------------------------------------------------------------------------
// biaffW (10,513,513) -> Wsp[n=kc*513+j][k] hi/lo bf16, K padded to 544 (zeros)
// ---------------------------------------------------------------------------
__global__ void wsplit_kernel(const float* __restrict__ W, u16* __restrict__ Wh,
                              u16* __restrict__ Wl)
{
    __shared__ float tile[32][33];
    int kc = blockIdx.z, k0 = blockIdx.x * 32, j0 = blockIdx.y * 32;
    int tx = threadIdx.x, ty = threadIdx.y;   // 32 x 8
#pragma unroll
    for (int yy = 0; yy < 32; yy += 8) {
        int k = k0 + ty + yy, j = j0 + tx;
        tile[ty + yy][tx] = (k < 513 && j < 513) ? W[((size_t)kc * 513 + k) * 513 + j] : 0.f;
    }
    __syncthreads();
#pragma unroll
    for (int yy = 0; yy < 32; yy += 8) {
        int j = j0 + ty + yy, k = k0 + tx;
        if (j < 513 && k < KP) {
            float v = tile[tx][ty + yy];
            size_t o = ((size_t)kc * 513 + j) * KP + k;
            u16 h = f2bf(v);
            Wh[o] = h; Wl[o] = f2bf(v - bf2f(h));
        }
    }
}

// ---------------------------------------------------------------------------
// Generic hi/lo bf16 MFMA GEMM: C[m,n] = act(A[m,:K].B[n,:K] + bias[n])
// act: 0 none, 1 gelu, 2 leaky, 3 per-column (n<1024 gelu else leaky)
// ---------------------------------------------------------------------------
__global__ __launch_bounds__(256)
void gemm_mfma_hl(const u16* __restrict__ Ah, const u16* __restrict__ Al,
                  const u16* __restrict__ Bh, const u16* __restrict__ Bl,
                  const float* __restrict__ bias, float* __restrict__ C,
                  int K, int ldc, int act)
{
    const int lane = threadIdx.x & 63, w = threadIdx.x >> 6;
    const int m0 = blockIdx.y * 64;
    const int n0 = blockIdx.x * 64 + w * 16;
    const int arow = m0 + (lane & 15);
    const int brow = n0 + (lane & 15);
    const int koff = (lane >> 4) * 8;
    f32x4 acc[4] = {};

    for (int k0 = 0; k0 < K; k0 += 32) {
        bf16x8 bh = *(const bf16x8*)(Bh + (size_t)brow * K + k0 + koff);
        bf16x8 bl = *(const bf16x8*)(Bl + (size_t)brow * K + k0 + koff);
#pragma unroll
        for (int mi = 0; mi < 4; ++mi) {
            size_t ao = (size_t)(arow + mi * 16) * K + k0 + koff;
            bf16x8 ah = *(const bf16x8*)(Ah + ao);
            bf16x8 al = *(const bf16x8*)(Al + ao);
            acc[mi] = __builtin_amdgcn_mfma_f32_16x16x32_bf16(ah, bh, acc[mi], 0, 0, 0);
            acc[mi] = __builtin_amdgcn_mfma_f32_16x16x32_bf16(ah, bl, acc[mi], 0, 0, 0);
            acc[mi] = __builtin_amdgcn_mfma_f32_16x16x32_bf16(al, bh, acc[mi], 0, 0, 0);
        }
    }
    const int cn = n0 + (lane & 15);
    const float bv = bias ? bias[cn] : 0.f;
    const int am = (act == 3) ? (cn < 1024 ? 1 : 2) : act;
#pragma unroll
    for (int mi = 0; mi < 4; ++mi)
#pragma unroll
        for (int r = 0; r < 4; ++r) {
            int m = m0 + mi * 16 + (lane >> 4) * 4 + r;
            float v = acc[mi][r] + bv;
            if (am == 1) v = 0.5f * v * (1.f + erff(v * 0.70710678118654752f));
            else if (am == 2) v = v > 0.f ? v : 0.01f * v;
            C[(size_t)m * ldc + cn] = v;
        }
}

// ---------------------------------------------------------------------------
// Biaffine M-GEMM (MFMA hi/lo) -> Mb hi/lo bf16 (pads pre-zeroed by memset)
// ---------------------------------------------------------------------------
__global__ __launch_bounds__(256)
void biaff_mfma(const u16* __restrict__ Ah, const u16* __restrict__ Al,
                const u16* __restrict__ Wh, const u16* __restrict__ Wl,
                u16* __restrict__ Mh, u16* __restrict__ Ml)
{
    const int lane = threadIdx.x & 63, w = threadIdx.x >> 6;
    const int m0 = blockIdx.y * 64;
    const int n0 = blockIdx.x * 128 + w * 32;
    const int arow = m0 + (lane & 15);
    const int koff = (lane >> 4) * 8;
    f32x4 acc[4][2] = {};

    for (int c = 0; c < 17; ++c) {
        const int k0 = c * 32 + koff;
        bf16x8 bh[2], bl[2];
#pragma unroll
        for (int ni = 0; ni < 2; ++ni) {
            size_t bo = (size_t)(n0 + ni * 16 + (lane & 15)) * KP + k0;
            bh[ni] = *(const bf16x8*)(Wh + bo);
            bl[ni] = *(const bf16x8*)(Wl + bo);
        }
#pragma unroll
        for (int mi = 0; mi < 4; ++mi) {
            size_t ao = (size_t)(arow + mi * 16) * KP + k0;
            bf16x8 ah = *(const bf16x8*)(Ah + ao);
            bf16x8 al = *(const bf16x8*)(Al + ao);
#pragma unroll
            for (int ni = 0; ni < 2; ++ni) {
                acc[mi][ni] = __builtin_amdgcn_mfma_f32_16x16x32_bf16(ah, bh[ni], acc[mi][ni], 0, 0, 0);
                acc[mi][ni] = __builtin_amdgcn_mfma_f32_16x16x32_bf16(ah, bl[ni], acc[mi][ni], 0, 0, 0);
                acc[mi][ni] = __builtin_amdgcn_mfma_f32_16x16x32_bf16(al, bh[ni], acc[mi][ni], 0, 0, 0);
            }
        }
    }
#pragma unroll
    for (int mi = 0; mi < 4; ++mi)
#pragma unroll
        for (int ni = 0; ni < 2; ++ni) {
            int n = n0 + ni * 16 + (lane & 15);
            if (n < NBIG) {
                int kc = n / PP, j = n - kc * PP;
#pragma unroll
                for (int r = 0; r < 4; ++r) {
                    int m = m0 + mi * 16 + (lane >> 4) * 4 + r;
                    float v = acc[mi][ni][r];
                    u16 h = f2bf(v);
                    size_t o = (size_t)m * (CLS * KP) + kc * KP + j;
                    Mh[o] = h; Ml[o] = f2bf(v - bf2f(h));
                }
            }
        }
}

// ---------------------------------------------------------------------------
// Final GEMM (MFMA hi/lo) + epilogue
// ---------------------------------------------------------------------------
__global__ __launch_bounds__(256)
void final_mfma(const u16* __restrict__ Mh, const u16* __restrict__ Ml,
                const u16* __restrict__ Th, const u16* __restrict__ Tl,
                const float* __restrict__ hv, const float* __restrict__ tv,
                const float* __restrict__ Tt, float* __restrict__ out)
{
    const int lane = threadIdx.x & 63, w = threadIdx.x >> 6;
    const int r0 = blockIdx.y * 64;
    const int b = r0 / 1920;
    const int rem = r0 - b * 1920;
    const int kc = rem / 192;
    const int x0 = rem - kc * 192;
    const int n0 = blockIdx.x * 64 + w * 16;
    const int koff = (lane >> 4) * 8;
    const size_t abase = (size_t)(b * 192 + x0 + (lane & 15)) * (CLS * KP) + kc * KP;
    const size_t bbase = (size_t)(b * 192 + n0 + (lane & 15)) * KP;
    f32x4 acc[4] = {};

    for (int c = 0; c < 17; ++c) {
        const int k0 = c * 32 + koff;
        bf16x8 bh = *(const bf16x8*)(Th + bbase + k0);
        bf16x8 bl = *(const bf16x8*)(Tl + bbase + k0);
#pragma unroll
        for (int mi = 0; mi < 4; ++mi) {
            size_t ao = abase + (size_t)mi * 16 * (CLS * KP) + k0;
            bf16x8 ah = *(const bf16x8*)(Mh + ao);
            bf16x8 al = *(const bf16x8*)(Ml + ao);
            acc[mi] = __builtin_amdgcn_mfma_f32_16x16x32_bf16(ah, bh, acc[mi], 0, 0, 0);
            acc[mi] = __builtin_amdgcn_mfma_f32_16x16x32_bf16(ah, bl, acc[mi], 0, 0, 0);
            acc[mi] = __builtin_amdgcn_mfma_f32_16x16x32_bf16(al, bh, acc[mi], 0, 0, 0);
        }
    }
    const int bk = b * 10 + kc;
    const int y = n0 + (lane & 15);
    const float tvv = tv[bk * 192 + y];
#pragma unroll
    for (int mi = 0; mi < 4; ++mi)
#pragma unroll
        for (int r = 0; r < 4; ++r) {
            int x = x0 + mi * 16 + (lane >> 4) * 4 + r;
            int d = y - x;
            d = d < -15 ? -15 : (d > 14 ? 14 : d);
            float v = acc[mi][r] + hv[bk * 192 + x] + tvv + Tt[kc * 30 + d + 15];
            out[(size_t)(bk * 192 + x) * 192 + y] = v;
        }
}

// ---------------------------------------------------------------------------
// Weight-stationary MFMA BiLSTM scan — ONE BLOCK PER DIRECTION (1024 threads,
// 16 waves x 64 cols). All h-exchange is LDS + __syncthreads; no global
// protocol. A rows 0-3 = h_hi(batch), 4-7 = h_lo (one MFMA covers both);
// rows 8-15 lanes read a fixed zero address (LDS broadcast, halves traffic).
// hi+lo summed in-register via shfl_xor(16) before the gates write.
// ---------------------------------------------------------------------------
__global__ __launch_bounds__(1024, 1)
void lstm_mfma(const float* __restrict__ xw, const u16* __restrict__ pw,
               const int* __restrict__ wl,
               u16* __restrict__ wrsh, u16* __restrict__ wrsl)
{
    const int dir = blockIdx.x;
    const int tid = threadIdx.x;
    const int lane = tid & 63, wid = tid >> 6;   // wid 0..15

    __shared__ __align__(16) u16 h_s[16 * 256];        // 8 KB; rows 0-3 hi, 4-7 lo, 8-15 zero
    __shared__ __align__(16) float gates_s[1024 * 4];  // 16 KB: [col][bb], XOR-swizzled

    for (int i = tid; i < 16 * 256; i += 1024) h_s[i] = 0;

    // stationary B-frags: 32 x 16B per lane (same per-wave size proven in r2/r3)
    bf16x8 bw[32];
    {
        const u16* base = pw + ((size_t)(dir * 16 + wid) * 32 * 64 + lane) * 8;
#pragma unroll
        for (int i = 0; i < 32; ++i)
            bw[i] = *reinterpret_cast<const bf16x8*>(base + (size_t)i * 64 * 8);
    }

    const int uu = tid >> 2, bb = tid & 3;       // uu 0..255: full hidden dim
    const int Lb = wl[bb];
    float c_state = 0.f, h_state = 0.f;

    const int row = lane & 15, quad = lane >> 4; // A: row=lane&15, k-chunk=lane>>4
    const int abase = row * 512 + quad * 16;
    const int aswz = (row & 7) << 4;
    const bool arow_live = row < 8;

    __syncthreads();

    int tt0 = dir ? (Lb - 1) : 0; if (tt0 < 0) tt0 = 0;
    const float* xr = xw + ((size_t)(bb * 192 + tt0)) * 2048 + dir * 1024 + uu;
    float x0 = xr[0], x1 = xr[256], x2 = xr[512], x3 = xr[768];

    f32x4 acc[4];
    for (int t = 0; t < LMAX; ++t) {
        // prefetch next-step x (independent of h; hides under MFMA phase)
        int ttn = dir ? (Lb - 2 - t) : (t + 1);
        if (ttn < 0) ttn = 0; if (ttn > 191) ttn = 191;
        const float* xrn = xw + ((size_t)(bb * 192 + ttn)) * 2048 + dir * 1024 + uu;
        float nx0 = xrn[0], nx1 = xrn[256], nx2 = xrn[512], nx3 = xrn[768];

        // ---- MFMA phase: 32 mfma/wave; zero rows read one broadcast address ----
#pragma unroll
        for (int tt = 0; tt < 4; ++tt) acc[tt] = (f32x4){0.f, 0.f, 0.f, 0.f};
#pragma unroll
        for (int kt = 0; kt < 8; ++kt) {
            int off = arow_live ? ((abase + kt * 64) ^ aswz) : (8 * 512);
            bf16x8 a = *reinterpret_cast<const bf16x8*>((const char*)h_s + off);
#pragma unroll
            for (int tt = 0; tt < 4; ++tt)
                acc[tt] = __builtin_amdgcn_mfma_f32_16x16x32_bf16(a, bw[kt * 4 + tt], acc[tt], 0, 0, 0);
        }

        // ---- hi+lo sum in-register: C rows 0-3 (quad0) += rows 4-7 (quad1) ----
#pragma unroll
        for (int tt = 0; tt < 4; ++tt)
#pragma unroll
            for (int r = 0; r < 4; ++r)
                acc[tt][r] += __shfl_xor(acc[tt][r], 16);

        if (lane < 16) {
#pragma unroll
            for (int tt = 0; tt < 4; ++tt) {
                int col = wid * 64 + tt * 16 + row;
                int gb = (col * 16) ^ (((col >> 2) & 7) << 4);
                *reinterpret_cast<f32x4*>((char*)gates_s + gb) = acc[tt];
            }
        }
        __syncthreads();

        // ---- update: one (unit, batch) per thread ----
        float gv[4];
#pragma unroll
        for (int g = 0; g < 4; ++g) {
            int col = uu * 4 + g;
            int gb = ((col * 16) ^ (((col >> 2) & 7) << 4)) + bb * 4;
            gv[g] = *reinterpret_cast<const float*>((const char*)gates_s + gb);
        }
        float gi = gv[0] + x0, gf = gv[1] + x1, gg = gv[2] + x2, go = gv[3] + x3;
        float cn = sigf(gf) * c_state + sigf(gi) * tanhf(gg);
        float hn = sigf(go) * tanhf(cn);
        if (t < Lb) { c_state = cn; h_state = hn; }
        u16 hb = f2bf(h_state);
        u16 lb = f2bf(h_state - bf2f(hb));
        if (t < Lb) {
            int ttok = dir ? (Lb - 1 - t) : t;
            size_t wo = ((size_t)(bb * 192 + ttok)) * 512 + dir * 256 + uu;
            wrsh[wo] = hb; wrsl[wo] = lb;
        }
        *(u16*)((char*)h_s + ((bb * 512 + uu * 2) ^ ((bb & 7) << 4))) = hb;
        *(u16*)((char*)h_s + (((bb + 4) * 512 + uu * 2) ^ (((bb + 4) & 7) << 4))) = lb;
        x0 = nx0; x1 = nx1; x2 = nx2; x3 = nx3;
        __syncthreads();
    }
}

// ---------------------------------------------------------------------------
// HT -> h1/t1 hi/lo splits with ones column, zero-padded to KP
// ---------------------------------------------------------------------------
__global__ void split_ht(const float* __restrict__ HT, u16* __restrict__ h1h,
                         u16* __restrict__ h1l, u16* __restrict__ t1h,
                         u16* __restrict__ t1l)
{
    int idx = blockIdx.x * blockDim.x + threadIdx.x;
    if (idx >= 768 * KP) return;
    int m = idx / KP, k = idx - m * KP;
    float hv = (k < 512) ? HT[(size_t)m * 2048 + k] : (k == 512 ? 1.f : 0.f);
    float tv = (k < 512) ? HT[(size_t)m * 2048 + 512 + k] : (k == 512 ? 1.f : 0.f);
    u16 hh = f2bf(hv);
    h1h[idx] = hh; h1l[idx] = f2bf(hv - bf2f(hh));
    u16 th = f2bf(tv);
    t1h[idx] = th; t1l[idx] = f2bf(tv - bf2f(th));
}

// ---------------------------------------------------------------------------
// hv/tv (wave-parallel) + Tt tables; blocks 0..39 hv/tv, 40..41 Tt
// ---------------------------------------------------------------------------
__global__ __launch_bounds__(256)
void hvtv_ttab(const float* __restrict__ HT, const float* __restrict__ Wco,
               const float* __restrict__ size_emb,
               float* __restrict__ hv, float* __restrict__ tv, float* __restrict__ Tt)
{
    int bk = blockIdx.x;
    if (bk < 40) {
        int b = bk / 10, k = bk - (bk / 10) * 10;
        int wave = threadIdx.x >> 6, lane = threadIdx.x & 63;
        const float* wk = Wco + k * WCO_LD;
        for (int x = wave; x < 192; x += 4) {
            const float* hrow = HT + (size_t)(b * 192 + x) * 2048 + 1024;
            float sh = 0.f, st = 0.f;
            for (int i = lane; i < 512; i += 64) {
                sh = fmaf(hrow[i], wk[i], sh);
                st = fmaf(hrow[512 + i], wk[513 + i], st);
            }
#pragma unroll
            for (int o = 32; o; o >>= 1) {
                sh += __shfl_down(sh, o);
                st += __shfl_down(st, o);
            }
            if (lane == 0) {
                hv[bk * 192 + x] = sh + wk[512];
                tv[bk * 192 + x] = st + wk[1025];
            }
        }
    } else {
        int idx = (bk - 40) * 256 + threadIdx.x;
        if (idx < 300) {
            int k = idx / 30, p = idx - (idx / 30) * 30;
            float s = 0.f;
            for (int e = 0; e < 25; ++e)
                s = fmaf(size_emb[p * 25 + e], Wco[k * WCO_LD + 1026 + e], s);
            Tt[idx] = s;
        }
    }
}

extern "C" void kernel_launch(void* const* d_in, const int* in_sizes, int n_in,
                              void* d_out, int out_size, void* d_ws, size_t ws_size,
                              hipStream_t stream)
{
    const float* word_reps = (const float*)d_in[0];
    const int*   word_length = (const int*)d_in[1];
    const float* Wih_f = (const float*)d_in[4];
    const float* Whh_f = (const float*)d_in[5];
    const float* b_f   = (const float*)d_in[6];
    const float* Wih_b = (const float*)d_in[7];
    const float* Whh_b = (const float*)d_in[8];
    const float* b_b   = (const float*)d_in[9];
    const float* mlp1_w = (const float*)d_in[20];
    const float* mlp1_b = (const float*)d_in[21];
    const float* mlp2_w = (const float*)d_in[22];
    const float* mlp2_b = (const float*)d_in[23];
    const float* head_w = (const float*)d_in[24];
    const float* head_b = (const float*)d_in[25];
    const float* tail_w = (const float*)d_in[26];
    const float* tail_b = (const float*)d_in[27];
    const float* biaffW = (const float*)d_in[28];
    const float* size_emb = (const float*)d_in[29];
    const float* W_co = (const float*)d_in[30];

    float* W = (float*)d_ws;
    // region A (dead after mid GEMM; reused by Mbh = [0, 2088960) f32)
    float* xw   = W;                               // [0, 1572864)
    u16*  wrsh  = (u16*)(W + 1572864);             // [1572864, 1769472)
    u16*  wrsl  = (u16*)(W + 1769472);             // [1769472, 1966080)
    u16*  pw    = (u16*)(W + 1966080);             // [1966080, 2228224)
    u16*  Mbh   = (u16*)W;                         // 4,177,920 u16 -> [0, 2088960) f32
    // stable
    float* HT   = W + 2228224;                     // [2228224, 3801088)
    u16* h1h = (u16*)(W + 3801088);
    u16* h1l = (u16*)(W + 4009984);
    u16* t1h = (u16*)(W + 4218880);
    u16* t1l = (u16*)(W + 4427776);
    u16* Wsph = (u16*)(W + 4636672);               // [4636672, 6064128)
    u16* Wspl = (u16*)(W + 6064128);               // [6064128, 7491584)
    u16* Mbl  = (u16*)(W + 7491584);               // [7491584, 9580544)
    //   overlay of Mbl region (dead before biaff): wih split + bias_ih
    u16* wihh = (u16*)(W + 7491584);
    u16* wihl = (u16*)(W + 8278016);
    float* bias_ih = W + 9064448;                  // 2048
    float* hv = W + 9580544;
    float* tv = W + 9588224;
    float* Tt = W + 9595904;                       // 304
    u16* wrph = (u16*)(W + 9604400);               // 589,824 u16
    u16* wrpl = (u16*)(W + 9899312);
    u16* mwh  = (u16*)(W + 10194224);              // 1,048,576 u16
    u16* mwl  = (u16*)(W + 10718512);
    float* bias_mid = W + 11242800;                // 2048
    // high-water ~11,244,848 f32 = 45.0 MB

    // wr rows t >= L must be exactly 0 (wrsh+wrsl contiguous)
    hipMemsetAsync(wrsh, 0, (size_t)393216 * 2 * sizeof(u16), stream);

    mega_prep<<<(3739648 + 255) / 256, 256, 0, stream>>>(
        word_reps, Wih_f, Wih_b, b_f, b_b,
        mlp1_w, mlp2_w, head_w, tail_w, mlp1_b, mlp2_b, head_b, tail_b,
        Whh_f, Whh_b,
        wrph, wrpl, wihh, wihl, bias_ih, mwh, mwl, bias_mid, pw);

    wsplit_kernel<<<dim3(17, 17, 10), dim3(32, 8), 0, stream>>>(biaffW, Wsph, Wspl);

    // xw = word_reps @ [Wih_f; Wih_b]^T + bias   (768 x 2048, one launch)
    gemm_mfma_hl<<<dim3(32, 12), 256, 0, stream>>>(wrph, wrpl, wihh, wihl, bias_ih, xw, 768, 2048, 0);

    // BiLSTM scan: one block per direction, exchange entirely in LDS
    lstm_mfma<<<2, 1024, 0, stream>>>(xw, pw, word_length, wrsh, wrsl);

    // HT = [gelu(wr@mlp1) | gelu(wr@mlp2) | leaky(wr@head) | leaky(wr@tail)]
    gemm_mfma_hl<<<dim3(32, 12), 256, 0, stream>>>(wrsh, wrsl, mwh, mwl, bias_mid, HT, 512, 2048, 3);

    split_ht<<<(768 * KP + 255) / 256, 256, 0, stream>>>(HT, h1h, h1l, t1h, t1l);
    hvtv_ttab<<<42, 256, 0, stream>>>(HT, W_co, size_emb, hv, tv, Tt);

    // Mb pad columns (j in [513,544)) must be ZERO: stale bytes as bf16 can be
    // NaN/Inf and NaN*0 = NaN in the final MFMA (round-5 lesson).
    hipMemsetAsync(Mbh, 0, (size_t)4177920 * 2, stream);
    hipMemsetAsync(Mbl, 0, (size_t)4177920 * 2, stream);

    biaff_mfma<<<dim3(41, 12), 256, 0, stream>>>(h1h, h1l, Wsph, Wspl, Mbh, Mbl);
    final_mfma<<<dim3(3, 120), 256, 0, stream>>>(Mbh, Mbl, t1h, t1l, hv, tv, Tt, (float*)d_out);
}

// Round 8
// 2075.761 us; speedup vs baseline: 1.0998x; 1.0998x over previous
//
#include <hip/hip_runtime.h>
#include <math.h>

// Problem constants
#define BB 4
#define NN 192
#define DIN 768
#define HD 256
#define HH 512
#define PP 513         // BIAFF+1
#define CLS 10
#define NBIG 5130      // CLS*PP
#define KP 544         // PP padded to 17*32
#define WCO_LD 1051
#define LMAX 192

typedef __attribute__((ext_vector_type(8))) __bf16 bf16x8;
typedef __attribute__((ext_vector_type(4))) float f32x4;
typedef unsigned short u16;
typedef unsigned int u32;
typedef unsigned long long u64;

__device__ __forceinline__ float sigf(float x) { return 1.f / (1.f + expf(-x)); }

__device__ __forceinline__ u16 f2bf(float f) {
    u32 x = __float_as_uint(f);
    u32 r = (x + 0x7FFF + ((x >> 16) & 1)) >> 16;
    return (u16)r;
}
__device__ __forceinline__ float bf2f(u16 h) {
    return __uint_as_float(((u32)h) << 16);
}

// ---------------------------------------------------------------------------
// mega_prep: all weight/input splits + LSTM weight packing in ONE launch.
// ---------------------------------------------------------------------------
__global__ void mega_prep(const float* __restrict__ word_reps,
                          const float* __restrict__ Wih_f, const float* __restrict__ Wih_b,
                          const float* __restrict__ b_f, const float* __restrict__ b_b,
                          const float* __restrict__ mlp1_w, const float* __restrict__ mlp2_w,
                          const float* __restrict__ head_w, const float* __restrict__ tail_w,
                          const float* __restrict__ mlp1_b, const float* __restrict__ mlp2_b,
                          const float* __restrict__ head_b, const float* __restrict__ tail_b,
                          const float* __restrict__ Whh_f, const float* __restrict__ Whh_b,
                          u16* __restrict__ wrph, u16* __restrict__ wrpl,
                          u16* __restrict__ wihh, u16* __restrict__ wihl, float* __restrict__ bias_ih,
                          u16* __restrict__ mwh, u16* __restrict__ mwl, float* __restrict__ bias_mid,
                          u16* __restrict__ pw)
{
    int i = blockIdx.x * blockDim.x + threadIdx.x;
    if (i < 589824) {
        float v = word_reps[i];
        u16 h = f2bf(v);
        wrph[i] = h; wrpl[i] = f2bf(v - bf2f(h));
        return;
    }
    i -= 589824;
    if (i < 1572864) {
        int n = i / 768, k = i - n * 768;
        float v = (n < 1024) ? Wih_f[(size_t)n * 768 + k] : Wih_b[(size_t)(n - 1024) * 768 + k];
        u16 h = f2bf(v);
        wihh[i] = h; wihl[i] = f2bf(v - bf2f(h));
        return;
    }
    i -= 1572864;
    if (i < 1048576) {
        int n = i >> 9, k = i & 511;
        const float* Ws = (n < 512) ? mlp1_w : (n < 1024) ? mlp2_w : (n < 1536) ? head_w : tail_w;
        float v = Ws[(size_t)(n & 511) * 512 + k];
        u16 h = f2bf(v);
        mwh[i] = h; mwl[i] = f2bf(v - bf2f(h));
        return;
    }
    i -= 1048576;
    if (i < 524288) {
        int f = i;
        int e = f & 7;
        int lane = (f >> 3) & 63;
        int frag = (f >> 9) & 31;
        int wave = (f >> 14) & 7;
        int dh = f >> 17;
        int dir = dh >> 1, half = dh & 1;
        int kt = frag >> 2, t = frag & 3;
        int col = half * 512 + wave * 64 + t * 16 + (lane & 15);
        int u = col >> 2, gt = col & 3;
        int g = gt * 256 + u;
        int k = kt * 32 + (lane >> 4) * 8 + e;
        const float* W = dir ? Whh_b : Whh_f;
        pw[f] = f2bf(W[(size_t)g * 256 + k]);
        return;
    }
    i -= 524288;
    if (i < 2048) {
        bias_ih[i] = (i < 1024) ? b_f[i] : b_b[i - 1024];
        return;
    }
    i -= 2048;
    if (i < 2048) {
        bias_mid[i] = (i < 512) ? mlp1_b[i] : (i < 1024) ? mlp2_b[i - 512]
                    : (i < 1536) ? head_b[i - 1024] : tail_b[i - 1536];
    }
}

// ---------------------------------------------------------------------------
// biaffW (10,513,513) -> Wsp[n=kc*513+j][k] hi/lo bf16, K padded to 544 (zeros)
// ---------------------------------------------------------------------------
__global__ void wsplit_kernel(const float* __restrict__ W, u16* __restrict__ Wh,
                              u16* __restrict__ Wl)
{
    __shared__ float tile[32][33];
    int kc = blockIdx.z, k0 = blockIdx.x * 32, j0 = blockIdx.y * 32;
    int tx = threadIdx.x, ty = threadIdx.y;   // 32 x 8
#pragma unroll
    for (int yy = 0; yy < 32; yy += 8) {
        int k = k0 + ty + yy, j = j0 + tx;
        tile[ty + yy][tx] = (k < 513 && j < 513) ? W[((size_t)kc * 513 + k) * 513 + j] : 0.f;
    }
    __syncthreads();
#pragma unroll
    for (int yy = 0; yy < 32; yy += 8) {
        int j = j0 + ty + yy, k = k0 + tx;
        if (j < 513 && k < KP) {
            float v = tile[tx][ty + yy];
            size_t o = ((size_t)kc * 513 + j) * KP + k;
            u16 h = f2bf(v);
            Wh[o] = h; Wl[o] = f2bf(v - bf2f(h));
        }
    }
}

// ---------------------------------------------------------------------------
// Generic hi/lo bf16 MFMA GEMM: C[m,n] = act(A[m,:K].B[n,:K] + bias[n])
// act: 0 none, 1 gelu, 2 leaky, 3 per-column (n<1024 gelu else leaky)
// ---------------------------------------------------------------------------
__global__ __launch_bounds__(256)
void gemm_mfma_hl(const u16* __restrict__ Ah, const u16* __restrict__ Al,
                  const u16* __restrict__ Bh, const u16* __restrict__ Bl,
                  const float* __restrict__ bias, float* __restrict__ C,
                  int K, int ldc, int act)
{
    const int lane = threadIdx.x & 63, w = threadIdx.x >> 6;
    const int m0 = blockIdx.y * 64;
    const int n0 = blockIdx.x * 64 + w * 16;
    const int arow = m0 + (lane & 15);
    const int brow = n0 + (lane & 15);
    const int koff = (lane >> 4) * 8;
    f32x4 acc[4] = {};

    for (int k0 = 0; k0 < K; k0 += 32) {
        bf16x8 bh = *(const bf16x8*)(Bh + (size_t)brow * K + k0 + koff);
        bf16x8 bl = *(const bf16x8*)(Bl + (size_t)brow * K + k0 + koff);
#pragma unroll
        for (int mi = 0; mi < 4; ++mi) {
            size_t ao = (size_t)(arow + mi * 16) * K + k0 + koff;
            bf16x8 ah = *(const bf16x8*)(Ah + ao);
            bf16x8 al = *(const bf16x8*)(Al + ao);
            acc[mi] = __builtin_amdgcn_mfma_f32_16x16x32_bf16(ah, bh, acc[mi], 0, 0, 0);
            acc[mi] = __builtin_amdgcn_mfma_f32_16x16x32_bf16(ah, bl, acc[mi], 0, 0, 0);
            acc[mi] = __builtin_amdgcn_mfma_f32_16x16x32_bf16(al, bh, acc[mi], 0, 0, 0);
        }
    }
    const int cn = n0 + (lane & 15);
    const float bv = bias ? bias[cn] : 0.f;
    const int am = (act == 3) ? (cn < 1024 ? 1 : 2) : act;
#pragma unroll
    for (int mi = 0; mi < 4; ++mi)
#pragma unroll
        for (int r = 0; r < 4; ++r) {
            int m = m0 + mi * 16 + (lane >> 4) * 4 + r;
            float v = acc[mi][r] + bv;
            if (am == 1) v = 0.5f * v * (1.f + erff(v * 0.70710678118654752f));
            else if (am == 2) v = v > 0.f ? v : 0.01f * v;
            C[(size_t)m * ldc + cn] = v;
        }
}

// ---------------------------------------------------------------------------
// Biaffine M-GEMM (MFMA hi/lo) -> Mb hi/lo bf16 (pads pre-zeroed by memset)
// ---------------------------------------------------------------------------
__global__ __launch_bounds__(256)
void biaff_mfma(const u16* __restrict__ Ah, const u16* __restrict__ Al,
                const u16* __restrict__ Wh, const u16* __restrict__ Wl,
                u16* __restrict__ Mh, u16* __restrict__ Ml)
{
    const int lane = threadIdx.x & 63, w = threadIdx.x >> 6;
    const int m0 = blockIdx.y * 64;
    const int n0 = blockIdx.x * 128 + w * 32;
    const int arow = m0 + (lane & 15);
    const int koff = (lane >> 4) * 8;
    f32x4 acc[4][2] = {};

    for (int c = 0; c < 17; ++c) {
        const int k0 = c * 32 + koff;
        bf16x8 bh[2], bl[2];
#pragma unroll
        for (int ni = 0; ni < 2; ++ni) {
            size_t bo = (size_t)(n0 + ni * 16 + (lane & 15)) * KP + k0;
            bh[ni] = *(const bf16x8*)(Wh + bo);
            bl[ni] = *(const bf16x8*)(Wl + bo);
        }
#pragma unroll
        for (int mi = 0; mi < 4; ++mi) {
            size_t ao = (size_t)(arow + mi * 16) * KP + k0;
            bf16x8 ah = *(const bf16x8*)(Ah + ao);
            bf16x8 al = *(const bf16x8*)(Al + ao);
#pragma unroll
            for (int ni = 0; ni < 2; ++ni) {
                acc[mi][ni] = __builtin_amdgcn_mfma_f32_16x16x32_bf16(ah, bh[ni], acc[mi][ni], 0, 0, 0);
                acc[mi][ni] = __builtin_amdgcn_mfma_f32_16x16x32_bf16(ah, bl[ni], acc[mi][ni], 0, 0, 0);
                acc[mi][ni] = __builtin_amdgcn_mfma_f32_16x16x32_bf16(al, bh[ni], acc[mi][ni], 0, 0, 0);
            }
        }
    }
#pragma unroll
    for (int mi = 0; mi < 4; ++mi)
#pragma unroll
        for (int ni = 0; ni < 2; ++ni) {
            int n = n0 + ni * 16 + (lane & 15);
            if (n < NBIG) {
                int kc = n / PP, j = n - kc * PP;
#pragma unroll
                for (int r = 0; r < 4; ++r) {
                    int m = m0 + mi * 16 + (lane >> 4) * 4 + r;
                    float v = acc[mi][ni][r];
                    u16 h = f2bf(v);
                    size_t o = (size_t)m * (CLS * KP) + kc * KP + j;
                    Mh[o] = h; Ml[o] = f2bf(v - bf2f(h));
                }
            }
        }
}

// ---------------------------------------------------------------------------
// Final GEMM (MFMA hi/lo) + epilogue
// ---------------------------------------------------------------------------
__global__ __launch_bounds__(256)
void final_mfma(const u16* __restrict__ Mh, const u16* __restrict__ Ml,
                const u16* __restrict__ Th, const u16* __restrict__ Tl,
                const float* __restrict__ hv, const float* __restrict__ tv,
                const float* __restrict__ Tt, float* __restrict__ out)
{
    const int lane = threadIdx.x & 63, w = threadIdx.x >> 6;
    const int r0 = blockIdx.y * 64;
    const int b = r0 / 1920;
    const int rem = r0 - b * 1920;
    const int kc = rem / 192;
    const int x0 = rem - kc * 192;
    const int n0 = blockIdx.x * 64 + w * 16;
    const int koff = (lane >> 4) * 8;
    const size_t abase = (size_t)(b * 192 + x0 + (lane & 15)) * (CLS * KP) + kc * KP;
    const size_t bbase = (size_t)(b * 192 + n0 + (lane & 15)) * KP;
    f32x4 acc[4] = {};

    for (int c = 0; c < 17; ++c) {
        const int k0 = c * 32 + koff;
        bf16x8 bh = *(const bf16x8*)(Th + bbase + k0);
        bf16x8 bl = *(const bf16x8*)(Tl + bbase + k0);
#pragma unroll
        for (int mi = 0; mi < 4; ++mi) {
            size_t ao = abase + (size_t)mi * 16 * (CLS * KP) + k0;
            bf16x8 ah = *(const bf16x8*)(Mh + ao);
            bf16x8 al = *(const bf16x8*)(Ml + ao);
            acc[mi] = __builtin_amdgcn_mfma_f32_16x16x32_bf16(ah, bh, acc[mi], 0, 0, 0);
            acc[mi] = __builtin_amdgcn_mfma_f32_16x16x32_bf16(ah, bl, acc[mi], 0, 0, 0);
            acc[mi] = __builtin_amdgcn_mfma_f32_16x16x32_bf16(al, bh, acc[mi], 0, 0, 0);
        }
    }
    const int bk = b * 10 + kc;
    const int y = n0 + (lane & 15);
    const float tvv = tv[bk * 192 + y];
#pragma unroll
    for (int mi = 0; mi < 4; ++mi)
#pragma unroll
        for (int r = 0; r < 4; ++r) {
            int x = x0 + mi * 16 + (lane >> 4) * 4 + r;
            int d = y - x;
            d = d < -15 ? -15 : (d > 14 ? 14 : d);
            float v = acc[mi][r] + hv[bk * 192 + x] + tvv + Tt[kc * 30 + d + 15];
            out[(size_t)(bk * 192 + x) * 192 + y] = v;
        }
}

// ---------------------------------------------------------------------------
// Weight-stationary MFMA BiLSTM scan — round-3 body VERBATIM, fused to one
// 1024-thread block per direction (16 waves x 64 cols = all 1024 gate cols).
// All h-exchange is LDS + __syncthreads; zero global protocol.
// ---------------------------------------------------------------------------
__global__ __launch_bounds__(1024, 1)
void lstm_mfma(const float* __restrict__ xw, const u16* __restrict__ pw,
               const int* __restrict__ wl,
               u16* __restrict__ wrsh, u16* __restrict__ wrsl)
{
    const int dir = blockIdx.x;
    const int tid = threadIdx.x;
    const int lane = tid & 63, wid = tid >> 6;     // wid 0..15
    const int half = wid >> 3, w8 = wid & 7;       // maps to r3's (dh, wave)

    __shared__ __align__(16) u16 h_hi[16 * 256];
    __shared__ __align__(16) u16 h_lo[16 * 256];
    __shared__ __align__(16) float gates_s[1024 * 4];

    for (int i = tid; i < 16 * 256; i += 1024) { h_hi[i] = 0; h_lo[i] = 0; }

    // stationary B-frags: 32 x 16B per lane (r3 layout: dh = dir*2+half, wave w8)
    bf16x8 bw[32];
    {
        const u16* base = pw + ((size_t)((dir * 2 + half) * 8 + w8) * 32 * 64 + lane) * 8;
#pragma unroll
        for (int i = 0; i < 32; ++i)
            bw[i] = *reinterpret_cast<const bf16x8*>(base + (size_t)i * 64 * 8);
    }

    const int uu = tid >> 2, bb = tid & 3;         // uu 0..255: full hidden dim
    const int Lb = wl[bb];
    float c_state = 0.f, h_state = 0.f;

    const int row = lane & 15, quad = lane >> 4;
    const int abase = row * 512 + quad * 16;
    const int aswz = (row & 7) << 4;
    const int wswz = bb << 4;

    __syncthreads();

    f32x4 acc[4];
    for (int t = 0; t < LMAX; ++t) {
        int ttok = dir ? (Lb - 1 - t) : t;
        if (ttok < 0) ttok = 0;
        const float* xrow = xw + ((size_t)(bb * 192 + ttok)) * 2048 + dir * 1024 + uu;
        float x0 = xrow[0], x1 = xrow[256], x2 = xrow[512], x3 = xrow[768];

        // ---- MFMA phase (r3-verbatim): 64 mfma/wave over h_hi + h_lo ----
#pragma unroll
        for (int tt = 0; tt < 4; ++tt) acc[tt] = (f32x4){0.f, 0.f, 0.f, 0.f};
#pragma unroll
        for (int kt = 0; kt < 8; ++kt) {
            int off = (abase + kt * 64) ^ aswz;
            bf16x8 ah = *reinterpret_cast<const bf16x8*>((const char*)h_hi + off);
            bf16x8 al = *reinterpret_cast<const bf16x8*>((const char*)h_lo + off);
#pragma unroll
            for (int tt = 0; tt < 4; ++tt) {
                acc[tt] = __builtin_amdgcn_mfma_f32_16x16x32_bf16(ah, bw[kt * 4 + tt], acc[tt], 0, 0, 0);
                acc[tt] = __builtin_amdgcn_mfma_f32_16x16x32_bf16(al, bw[kt * 4 + tt], acc[tt], 0, 0, 0);
            }
        }
        if (lane < 16) {
#pragma unroll
            for (int tt = 0; tt < 4; ++tt) {
                int col = wid * 64 + tt * 16 + lane;
                *reinterpret_cast<f32x4*>(&gates_s[col * 4]) = acc[tt];
            }
        }
        __syncthreads();

        // ---- update: one (unit, batch) per thread ----
        float gi = gates_s[(uu * 4 + 0) * 4 + bb] + x0;
        float gf = gates_s[(uu * 4 + 1) * 4 + bb] + x1;
        float gg = gates_s[(uu * 4 + 2) * 4 + bb] + x2;
        float go = gates_s[(uu * 4 + 3) * 4 + bb] + x3;
        float cn = sigf(gf) * c_state + sigf(gi) * tanhf(gg);
        float hn = sigf(go) * tanhf(cn);
        if (t < Lb) { c_state = cn; h_state = hn; }
        u16 hb = f2bf(h_state);
        u16 lb = f2bf(h_state - bf2f(hb));
        if (t < Lb) {
            size_t wo = ((size_t)(bb * 192 + ttok)) * 512 + dir * 256 + uu;
            wrsh[wo] = hb; wrsl[wo] = lb;
        }
        *(u16*)((char*)h_hi + ((bb * 512 + uu * 2) ^ wswz)) = hb;
        *(u16*)((char*)h_lo + ((bb * 512 + uu * 2) ^ wswz)) = lb;
        __syncthreads();
    }
}

// ---------------------------------------------------------------------------
// HT -> h1/t1 hi/lo splits with ones column, zero-padded to KP
// ---------------------------------------------------------------------------
__global__ void split_ht(const float* __restrict__ HT, u16* __restrict__ h1h,
                         u16* __restrict__ h1l, u16* __restrict__ t1h,
                         u16* __restrict__ t1l)
{
    int idx = blockIdx.x * blockDim.x + threadIdx.x;
    if (idx >= 768 * KP) return;
    int m = idx / KP, k = idx - m * KP;
    float hv = (k < 512) ? HT[(size_t)m * 2048 + k] : (k == 512 ? 1.f : 0.f);
    float tv = (k < 512) ? HT[(size_t)m * 2048 + 512 + k] : (k == 512 ? 1.f : 0.f);
    u16 hh = f2bf(hv);
    h1h[idx] = hh; h1l[idx] = f2bf(hv - bf2f(hh));
    u16 th = f2bf(tv);
    t1h[idx] = th; t1l[idx] = f2bf(tv - bf2f(th));
}

// ---------------------------------------------------------------------------
// hv/tv (wave-parallel) + Tt tables; blocks 0..39 hv/tv, 40..41 Tt
// ---------------------------------------------------------------------------
__global__ __launch_bounds__(256)
void hvtv_ttab(const float* __restrict__ HT, const float* __restrict__ Wco,
               const float* __restrict__ size_emb,
               float* __restrict__ hv, float* __restrict__ tv, float* __restrict__ Tt)
{
    int bk = blockIdx.x;
    if (bk < 40) {
        int b = bk / 10, k = bk - (bk / 10) * 10;
        int wave = threadIdx.x >> 6, lane = threadIdx.x & 63;
        const float* wk = Wco + k * WCO_LD;
        for (int x = wave; x < 192; x += 4) {
            const float* hrow = HT + (size_t)(b * 192 + x) * 2048 + 1024;
            float sh = 0.f, st = 0.f;
            for (int i = lane; i < 512; i += 64) {
                sh = fmaf(hrow[i], wk[i], sh);
                st = fmaf(hrow[512 + i], wk[513 + i], st);
            }
#pragma unroll
            for (int o = 32; o; o >>= 1) {
                sh += __shfl_down(sh, o);
                st += __shfl_down(st, o);
            }
            if (lane == 0) {
                hv[bk * 192 + x] = sh + wk[512];
                tv[bk * 192 + x] = st + wk[1025];
            }
        }
    } else {
        int idx = (bk - 40) * 256 + threadIdx.x;
        if (idx < 300) {
            int k = idx / 30, p = idx - (idx / 30) * 30;
            float s = 0.f;
            for (int e = 0; e < 25; ++e)
                s = fmaf(size_emb[p * 25 + e], Wco[k * WCO_LD + 1026 + e], s);
            Tt[idx] = s;
        }
    }
}

extern "C" void kernel_launch(void* const* d_in, const int* in_sizes, int n_in,
                              void* d_out, int out_size, void* d_ws, size_t ws_size,
                              hipStream_t stream)
{
    const float* word_reps = (const float*)d_in[0];
    const int*   word_length = (const int*)d_in[1];
    const float* Wih_f = (const float*)d_in[4];
    const float* Whh_f = (const float*)d_in[5];
    const float* b_f   = (const float*)d_in[6];
    const float* Wih_b = (const float*)d_in[7];
    const float* Whh_b = (const float*)d_in[8];
    const float* b_b   = (const float*)d_in[9];
    const float* mlp1_w = (const float*)d_in[20];
    const float* mlp1_b = (const float*)d_in[21];
    const float* mlp2_w = (const float*)d_in[22];
    const float* mlp2_b = (const float*)d_in[23];
    const float* head_w = (const float*)d_in[24];
    const float* head_b = (const float*)d_in[25];
    const float* tail_w = (const float*)d_in[26];
    const float* tail_b = (const float*)d_in[27];
    const float* biaffW = (const float*)d_in[28];
    const float* size_emb = (const float*)d_in[29];
    const float* W_co = (const float*)d_in[30];

    float* W = (float*)d_ws;
    // region A (dead after mid GEMM; reused by Mbh = [0, 2088960) f32)
    float* xw   = W;                               // [0, 1572864)
    u16*  wrsh  = (u16*)(W + 1572864);             // [1572864, 1769472)
    u16*  wrsl  = (u16*)(W + 1769472);             // [1769472, 1966080)
    u16*  pw    = (u16*)(W + 1966080);             // [1966080, 2228224)
    u16*  Mbh   = (u16*)W;                         // 4,177,920 u16 -> [0, 2088960) f32
    // stable
    float* HT   = W + 2228224;                     // [2228224, 3801088)
    u16* h1h = (u16*)(W + 3801088);
    u16* h1l = (u16*)(W + 4009984);
    u16* t1h = (u16*)(W + 4218880);
    u16* t1l = (u16*)(W + 4427776);
    u16* Wsph = (u16*)(W + 4636672);               // [4636672, 6064128)
    u16* Wspl = (u16*)(W + 6064128);               // [6064128, 7491584)
    u16* Mbl  = (u16*)(W + 7491584);               // [7491584, 9580544)
    //   overlay of Mbl region (dead before biaff): wih split + bias_ih
    u16* wihh = (u16*)(W + 7491584);
    u16* wihl = (u16*)(W + 8278016);
    float* bias_ih = W + 9064448;                  // 2048
    float* hv = W + 9580544;
    float* tv = W + 9588224;
    float* Tt = W + 9595904;                       // 304
    u16* wrph = (u16*)(W + 9604400);               // 589,824 u16
    u16* wrpl = (u16*)(W + 9899312);
    u16* mwh  = (u16*)(W + 10194224);              // 1,048,576 u16
    u16* mwl  = (u16*)(W + 10718512);
    float* bias_mid = W + 11242800;                // 2048
    // high-water ~11,244,848 f32 = 45.0 MB

    // wr rows t >= L must be exactly 0 (wrsh+wrsl contiguous)
    hipMemsetAsync(wrsh, 0, (size_t)393216 * 2 * sizeof(u16), stream);

    mega_prep<<<(3739648 + 255) / 256, 256, 0, stream>>>(
        word_reps, Wih_f, Wih_b, b_f, b_b,
        mlp1_w, mlp2_w, head_w, tail_w, mlp1_b, mlp2_b, head_b, tail_b,
        Whh_f, Whh_b,
        wrph, wrpl, wihh, wihl, bias_ih, mwh, mwl, bias_mid, pw);

    wsplit_kernel<<<dim3(17, 17, 10), dim3(32, 8), 0, stream>>>(biaffW, Wsph, Wspl);

    // xw = word_reps @ [Wih_f; Wih_b]^T + bias   (768 x 2048, one launch)
    gemm_mfma_hl<<<dim3(32, 12), 256, 0, stream>>>(wrph, wrpl, wihh, wihl, bias_ih, xw, 768, 2048, 0);

    // BiLSTM scan: one block per direction, r3 body, exchange entirely in LDS
    lstm_mfma<<<2, 1024, 0, stream>>>(xw, pw, word_length, wrsh, wrsl);

    // HT = [gelu(wr@mlp1) | gelu(wr@mlp2) | leaky(wr@head) | leaky(wr@tail)]
    gemm_mfma_hl<<<dim3(32, 12), 256, 0, stream>>>(wrsh, wrsl, mwh, mwl, bias_mid, HT, 512, 2048, 3);

    split_ht<<<(768 * KP + 255) / 256, 256, 0, stream>>>(HT, h1h, h1l, t1h, t1l);
    hvtv_ttab<<<42, 256, 0, stream>>>(HT, W_co, size_emb, hv, tv, Tt);

    // Mb pad columns (j in [513,544)) must be ZERO: stale bytes as bf16 can be
    // NaN/Inf and NaN*0 = NaN in the final MFMA (round-5 lesson).
    hipMemsetAsync(Mbh, 0, (size_t)4177920 * 2, stream);
    hipMemsetAsync(Mbl, 0, (size_t)4177920 * 2, stream);

    biaff_mfma<<<dim3(41, 12), 256, 0, stream>>>(h1h, h1l, Wsph, Wspl, Mbh, Mbl);
    final_mfma<<<dim3(3, 120), 256, 0, stream>>>(Mbh, Mbl, t1h, t1l, hv, tv, Tt, (float*)d_out);
}

// Round 9
// 860.355 us; speedup vs baseline: 2.6536x; 2.4127x over previous
//
#include <hip/hip_runtime.h>
#include <math.h>

// Problem constants
#define BB 4
#define NN 192
#define DIN 768
#define HD 256
#define HH 512
#define PP 513         // BIAFF+1
#define CLS 10
#define NBIG 5130      // CLS*PP
#define KP 544         // PP padded to 17*32
#define WCO_LD 1051
#define LMAX 192

typedef __attribute__((ext_vector_type(8))) __bf16 bf16x8;
typedef __attribute__((ext_vector_type(4))) float f32x4;
typedef unsigned short u16;
typedef unsigned int u32;
typedef unsigned long long u64;

__device__ __forceinline__ float sigf(float x) { return 1.f / (1.f + expf(-x)); }

__device__ __forceinline__ u16 f2bf(float f) {
    u32 x = __float_as_uint(f);
    u32 r = (x + 0x7FFF + ((x >> 16) & 1)) >> 16;
    return (u16)r;
}
__device__ __forceinline__ float bf2f(u16 h) {
    return __uint_as_float(((u32)h) << 16);
}

// ---------------------------------------------------------------------------
// mega_prep: all weight/input splits + LSTM weight packing in ONE launch.
// pack_w layout (r3 4-block scheme): [dh(4)][wave(8)][frag(32)][lane(64)][e(8)]
// ---------------------------------------------------------------------------
__global__ void mega_prep(const float* __restrict__ word_reps,
                          const float* __restrict__ Wih_f, const float* __restrict__ Wih_b,
                          const float* __restrict__ b_f, const float* __restrict__ b_b,
                          const float* __restrict__ mlp1_w, const float* __restrict__ mlp2_w,
                          const float* __restrict__ head_w, const float* __restrict__ tail_w,
                          const float* __restrict__ mlp1_b, const float* __restrict__ mlp2_b,
                          const float* __restrict__ head_b, const float* __restrict__ tail_b,
                          const float* __restrict__ Whh_f, const float* __restrict__ Whh_b,
                          u16* __restrict__ wrph, u16* __restrict__ wrpl,
                          u16* __restrict__ wihh, u16* __restrict__ wihl, float* __restrict__ bias_ih,
                          u16* __restrict__ mwh, u16* __restrict__ mwl, float* __restrict__ bias_mid,
                          u16* __restrict__ pw)
{
    int i = blockIdx.x * blockDim.x + threadIdx.x;
    if (i < 589824) {
        float v = word_reps[i];
        u16 h = f2bf(v);
        wrph[i] = h; wrpl[i] = f2bf(v - bf2f(h));
        return;
    }
    i -= 589824;
    if (i < 1572864) {
        int n = i / 768, k = i - n * 768;
        float v = (n < 1024) ? Wih_f[(size_t)n * 768 + k] : Wih_b[(size_t)(n - 1024) * 768 + k];
        u16 h = f2bf(v);
        wihh[i] = h; wihl[i] = f2bf(v - bf2f(h));
        return;
    }
    i -= 1572864;
    if (i < 1048576) {
        int n = i >> 9, k = i & 511;
        const float* Ws = (n < 512) ? mlp1_w : (n < 1024) ? mlp2_w : (n < 1536) ? head_w : tail_w;
        float v = Ws[(size_t)(n & 511) * 512 + k];
        u16 h = f2bf(v);
        mwh[i] = h; mwl[i] = f2bf(v - bf2f(h));
        return;
    }
    i -= 1048576;
    if (i < 524288) {
        int f = i;
        int e = f & 7;
        int lane = (f >> 3) & 63;
        int frag = (f >> 9) & 31;
        int wave = (f >> 14) & 7;
        int dh = f >> 17;
        int dir = dh >> 1, half = dh & 1;
        int kt = frag >> 2, t = frag & 3;
        int col = half * 512 + wave * 64 + t * 16 + (lane & 15);
        int u = col >> 2, gt = col & 3;
        int g = gt * 256 + u;
        int k = kt * 32 + (lane >> 4) * 8 + e;
        const float* W = dir ? Whh_b : Whh_f;
        pw[f] = f2bf(W[(size_t)g * 256 + k]);
        return;
    }
    i -= 524288;
    if (i < 2048) {
        bias_ih[i] = (i < 1024) ? b_f[i] : b_b[i - 1024];
        return;
    }
    i -= 2048;
    if (i < 2048) {
        bias_mid[i] = (i < 512) ? mlp1_b[i] : (i < 1024) ? mlp2_b[i - 512]
                    : (i < 1536) ? head_b[i - 1024] : tail_b[i - 1536];
    }
}

// ---------------------------------------------------------------------------
// biaffW (10,513,513) -> Wsp[n=kc*513+j][k] hi/lo bf16, K padded to 544 (zeros)
// ---------------------------------------------------------------------------
__global__ void wsplit_kernel(const float* __restrict__ W, u16* __restrict__ Wh,
                              u16* __restrict__ Wl)
{
    __shared__ float tile[32][33];
    int kc = blockIdx.z, k0 = blockIdx.x * 32, j0 = blockIdx.y * 32;
    int tx = threadIdx.x, ty = threadIdx.y;   // 32 x 8
#pragma unroll
    for (int yy = 0; yy < 32; yy += 8) {
        int k = k0 + ty + yy, j = j0 + tx;
        tile[ty + yy][tx] = (k < 513 && j < 513) ? W[((size_t)kc * 513 + k) * 513 + j] : 0.f;
    }
    __syncthreads();
#pragma unroll
    for (int yy = 0; yy < 32; yy += 8) {
        int j = j0 + ty + yy, k = k0 + tx;
        if (j < 513 && k < KP) {
            float v = tile[tx][ty + yy];
            size_t o = ((size_t)kc * 513 + j) * KP + k;
            u16 h = f2bf(v);
            Wh[o] = h; Wl[o] = f2bf(v - bf2f(h));
        }
    }
}

// ---------------------------------------------------------------------------
// Generic hi/lo bf16 MFMA GEMM: C[m,n] = act(A[m,:K].B[n,:K] + bias[n])
// act: 0 none, 1 gelu, 2 leaky, 3 per-column (n<1024 gelu else leaky)
// ---------------------------------------------------------------------------
__global__ __launch_bounds__(256)
void gemm_mfma_hl(const u16* __restrict__ Ah, const u16* __restrict__ Al,
                  const u16* __restrict__ Bh, const u16* __restrict__ Bl,
                  const float* __restrict__ bias, float* __restrict__ C,
                  int K, int ldc, int act)
{
    const int lane = threadIdx.x & 63, w = threadIdx.x >> 6;
    const int m0 = blockIdx.y * 64;
    const int n0 = blockIdx.x * 64 + w * 16;
    const int arow = m0 + (lane & 15);
    const int brow = n0 + (lane & 15);
    const int koff = (lane >> 4) * 8;
    f32x4 acc[4] = {};

    for (int k0 = 0; k0 < K; k0 += 32) {
        bf16x8 bh = *(const bf16x8*)(Bh + (size_t)brow * K + k0 + koff);
        bf16x8 bl = *(const bf16x8*)(Bl + (size_t)brow * K + k0 + koff);
#pragma unroll
        for (int mi = 0; mi < 4; ++mi) {
            size_t ao = (size_t)(arow + mi * 16) * K + k0 + koff;
            bf16x8 ah = *(const bf16x8*)(Ah + ao);
            bf16x8 al = *(const bf16x8*)(Al + ao);
            acc[mi] = __builtin_amdgcn_mfma_f32_16x16x32_bf16(ah, bh, acc[mi], 0, 0, 0);
            acc[mi] = __builtin_amdgcn_mfma_f32_16x16x32_bf16(ah, bl, acc[mi], 0, 0, 0);
            acc[mi] = __builtin_amdgcn_mfma_f32_16x16x32_bf16(al, bh, acc[mi], 0, 0, 0);
        }
    }
    const int cn = n0 + (lane & 15);
    const float bv = bias ? bias[cn] : 0.f;
    const int am = (act == 3) ? (cn < 1024 ? 1 : 2) : act;
#pragma unroll
    for (int mi = 0; mi < 4; ++mi)
#pragma unroll
        for (int r = 0; r < 4; ++r) {
            int m = m0 + mi * 16 + (lane >> 4) * 4 + r;
            float v = acc[mi][r] + bv;
            if (am == 1) v = 0.5f * v * (1.f + erff(v * 0.70710678118654752f));
            else if (am == 2) v = v > 0.f ? v : 0.01f * v;
            C[(size_t)m * ldc + cn] = v;
        }
}

// ---------------------------------------------------------------------------
// Biaffine M-GEMM (MFMA hi/lo) -> Mb hi/lo bf16 (pads pre-zeroed by memset)
// ---------------------------------------------------------------------------
__global__ __launch_bounds__(256)
void biaff_mfma(const u16* __restrict__ Ah, const u16* __restrict__ Al,
                const u16* __restrict__ Wh, const u16* __restrict__ Wl,
                u16* __restrict__ Mh, u16* __restrict__ Ml)
{
    const int lane = threadIdx.x & 63, w = threadIdx.x >> 6;
    const int m0 = blockIdx.y * 64;
    const int n0 = blockIdx.x * 128 + w * 32;
    const int arow = m0 + (lane & 15);
    const int koff = (lane >> 4) * 8;
    f32x4 acc[4][2] = {};

    for (int c = 0; c < 17; ++c) {
        const int k0 = c * 32 + koff;
        bf16x8 bh[2], bl[2];
#pragma unroll
        for (int ni = 0; ni < 2; ++ni) {
            size_t bo = (size_t)(n0 + ni * 16 + (lane & 15)) * KP + k0;
            bh[ni] = *(const bf16x8*)(Wh + bo);
            bl[ni] = *(const bf16x8*)(Wl + bo);
        }
#pragma unroll
        for (int mi = 0; mi < 4; ++mi) {
            size_t ao = (size_t)(arow + mi * 16) * KP + k0;
            bf16x8 ah = *(const bf16x8*)(Ah + ao);
            bf16x8 al = *(const bf16x8*)(Al + ao);
#pragma unroll
            for (int ni = 0; ni < 2; ++ni) {
                acc[mi][ni] = __builtin_amdgcn_mfma_f32_16x16x32_bf16(ah, bh[ni], acc[mi][ni], 0, 0, 0);
                acc[mi][ni] = __builtin_amdgcn_mfma_f32_16x16x32_bf16(ah, bl[ni], acc[mi][ni], 0, 0, 0);
                acc[mi][ni] = __builtin_amdgcn_mfma_f32_16x16x32_bf16(al, bh[ni], acc[mi][ni], 0, 0, 0);
            }
        }
    }
#pragma unroll
    for (int mi = 0; mi < 4; ++mi)
#pragma unroll
        for (int ni = 0; ni < 2; ++ni) {
            int n = n0 + ni * 16 + (lane & 15);
            if (n < NBIG) {
                int kc = n / PP, j = n - kc * PP;
#pragma unroll
                for (int r = 0; r < 4; ++r) {
                    int m = m0 + mi * 16 + (lane >> 4) * 4 + r;
                    float v = acc[mi][ni][r];
                    u16 h = f2bf(v);
                    size_t o = (size_t)m * (CLS * KP) + kc * KP + j;
                    Mh[o] = h; Ml[o] = f2bf(v - bf2f(h));
                }
            }
        }
}

// ---------------------------------------------------------------------------
// Final GEMM (MFMA hi/lo) + epilogue
// ---------------------------------------------------------------------------
__global__ __launch_bounds__(256)
void final_mfma(const u16* __restrict__ Mh, const u16* __restrict__ Ml,
                const u16* __restrict__ Th, const u16* __restrict__ Tl,
                const float* __restrict__ hv, const float* __restrict__ tv,
                const float* __restrict__ Tt, float* __restrict__ out)
{
    const int lane = threadIdx.x & 63, w = threadIdx.x >> 6;
    const int r0 = blockIdx.y * 64;
    const int b = r0 / 1920;
    const int rem = r0 - b * 1920;
    const int kc = rem / 192;
    const int x0 = rem - kc * 192;
    const int n0 = blockIdx.x * 64 + w * 16;
    const int koff = (lane >> 4) * 8;
    const size_t abase = (size_t)(b * 192 + x0 + (lane & 15)) * (CLS * KP) + kc * KP;
    const size_t bbase = (size_t)(b * 192 + n0 + (lane & 15)) * KP;
    f32x4 acc[4] = {};

    for (int c = 0; c < 17; ++c) {
        const int k0 = c * 32 + koff;
        bf16x8 bh = *(const bf16x8*)(Th + bbase + k0);
        bf16x8 bl = *(const bf16x8*)(Tl + bbase + k0);
#pragma unroll
        for (int mi = 0; mi < 4; ++mi) {
            size_t ao = abase + (size_t)mi * 16 * (CLS * KP) + k0;
            bf16x8 ah = *(const bf16x8*)(Mh + ao);
            bf16x8 al = *(const bf16x8*)(Ml + ao);
            acc[mi] = __builtin_amdgcn_mfma_f32_16x16x32_bf16(ah, bh, acc[mi], 0, 0, 0);
            acc[mi] = __builtin_amdgcn_mfma_f32_16x16x32_bf16(ah, bl, acc[mi], 0, 0, 0);
            acc[mi] = __builtin_amdgcn_mfma_f32_16x16x32_bf16(al, bh, acc[mi], 0, 0, 0);
        }
    }
    const int bk = b * 10 + kc;
    const int y = n0 + (lane & 15);
    const float tvv = tv[bk * 192 + y];
#pragma unroll
    for (int mi = 0; mi < 4; ++mi)
#pragma unroll
        for (int r = 0; r < 4; ++r) {
            int x = x0 + mi * 16 + (lane >> 4) * 4 + r;
            int d = y - x;
            d = d < -15 ? -15 : (d > 14 ? 14 : d);
            float v = acc[mi][r] + hv[bk * 192 + x] + tvv + Tt[kc * 30 + d + 15];
            out[(size_t)(bk * 192 + x) * 192 + y] = v;
        }
}

// ---------------------------------------------------------------------------
// Weight-stationary MFMA BiLSTM scan — round-3 protocol & body VERBATIM.
// 4 blocks (dh = dir*2+half), 512 threads, stamped-u64 agent-atomic exchange.
// ONLY deltas vs r3: __launch_bounds__(512, 1) so the 128-VGPR bw[32] array is
// truly register-resident (2 waves/SIMD -> 256-reg budget; r3's (512,2) forced
// a 128-reg budget and spilled the weights -> per-step scratch streaming), and
// h written out as u16 hi/lo pair.
// ---------------------------------------------------------------------------
__global__ __launch_bounds__(512, 1)
void lstm_mfma(const float* __restrict__ xw, const u16* __restrict__ pw,
               const int* __restrict__ wl,
               u16* __restrict__ wrsh, u16* __restrict__ wrsl,
               u64* __restrict__ ex)
{
    const int dh = blockIdx.x;            // 0..3
    const int dir = dh >> 1, half = dh & 1;
    const int tid = threadIdx.x;
    const int lane = tid & 63, wid = tid >> 6;

    __shared__ __align__(16) u16 h_hi[16 * 256];
    __shared__ __align__(16) u16 h_lo[16 * 256];
    __shared__ __align__(16) float gates_s[512 * 4];

    for (int i = tid; i < 16 * 256; i += 512) { h_hi[i] = 0; h_lo[i] = 0; }

    // stationary B-frags: 32 x 16B per lane = 128 VGPRs (resident at 256-budget)
    bf16x8 bw[32];
    {
        const u16* base = pw + ((size_t)(dh * 8 + wid) * 32 * 64 + lane) * 8;
#pragma unroll
        for (int i = 0; i < 32; ++i)
            bw[i] = *reinterpret_cast<const bf16x8*>(base + (size_t)i * 64 * 8);
    }

    const int u_loc = tid >> 2, bb = tid & 3;
    const int u_glob = half * 128 + u_loc;
    const int Lb = wl[bb];
    float c_state = 0.f, h_state = 0.f;

    const int row = lane & 15, quad = lane >> 4;
    const int abase = row * 512 + quad * 16;
    const int aswz = (row & 7) << 4;
    const int wswz = bb << 4;

    __syncthreads();

    f32x4 acc[4];
    for (int t = 0; t < LMAX; ++t) {
        int ttok = (dir == 0) ? t : (Lb - 1 - t);
        if (ttok < 0) ttok = 0;
        const float* xrow = xw + ((size_t)(bb * 192 + ttok)) * 2048 + dir * 1024 + u_glob;
        float x0 = xrow[0], x1 = xrow[256], x2 = xrow[512], x3 = xrow[768];

        // ---- MFMA phase ----
#pragma unroll
        for (int tt = 0; tt < 4; ++tt) acc[tt] = (f32x4){0.f, 0.f, 0.f, 0.f};
#pragma unroll
        for (int kt = 0; kt < 8; ++kt) {
            int off = (abase + kt * 64) ^ aswz;
            bf16x8 ah = *reinterpret_cast<const bf16x8*>((const char*)h_hi + off);
            bf16x8 al = *reinterpret_cast<const bf16x8*>((const char*)h_lo + off);
#pragma unroll
            for (int tt = 0; tt < 4; ++tt) {
                acc[tt] = __builtin_amdgcn_mfma_f32_16x16x32_bf16(ah, bw[kt * 4 + tt], acc[tt], 0, 0, 0);
                acc[tt] = __builtin_amdgcn_mfma_f32_16x16x32_bf16(al, bw[kt * 4 + tt], acc[tt], 0, 0, 0);
            }
        }
        if (lane < 16) {
#pragma unroll
            for (int tt = 0; tt < 4; ++tt) {
                int col_loc = wid * 64 + tt * 16 + lane;
                *reinterpret_cast<f32x4*>(&gates_s[col_loc * 4]) = acc[tt];
            }
        }
        __syncthreads();

        // ---- update phase: one (unit, batch) per thread ----
        float gi = gates_s[(u_loc * 4 + 0) * 4 + bb] + x0;
        float gf = gates_s[(u_loc * 4 + 1) * 4 + bb] + x1;
        float gg = gates_s[(u_loc * 4 + 2) * 4 + bb] + x2;
        float go = gates_s[(u_loc * 4 + 3) * 4 + bb] + x3;
        float cn = sigf(gf) * c_state + sigf(gi) * tanhf(gg);
        float hn = sigf(go) * tanhf(cn);
        if (t < Lb) { c_state = cn; h_state = hn; }
        u16 hi_b = f2bf(h_state);
        u16 lo_b = f2bf(h_state - bf2f(hi_b));
        if (t < Lb) {
            size_t wo = ((size_t)(bb * 192 + ttok)) * 512 + dir * 256 + u_glob;
            wrsh[wo] = hi_b; wrsl[wo] = lo_b;
        }
        {
            int lb = (bb * 512 + u_glob * 2) ^ wswz;
            *(u16*)((char*)h_hi + lb) = hi_b;
            *(u16*)((char*)h_lo + lb) = lo_b;
        }
        u32 packv = ((u32)lo_b << 16) | hi_b;

        // ---- stamped 64b exchange (r3-verbatim) ----
        u64 vv = (u64)packv | ((u64)(u32)(t + 1) << 32);
        __hip_atomic_store(&ex[((size_t)dh * 2 + (t & 1)) * 512 + tid], vv,
                           __ATOMIC_RELAXED, __HIP_MEMORY_SCOPE_AGENT);
        u64 pv;
        do {
            pv = __hip_atomic_load(&ex[((size_t)(dh ^ 1) * 2 + (t & 1)) * 512 + tid],
                                   __ATOMIC_RELAXED, __HIP_MEMORY_SCOPE_AGENT);
            if ((u32)(pv >> 32) == (u32)(t + 1)) break;
            __builtin_amdgcn_s_sleep(1);
        } while (true);
        {
            u32 pk = (u32)pv;
            int pu = (half ^ 1) * 128 + (tid >> 2);
            int lb = (bb * 512 + pu * 2) ^ wswz;
            *(u16*)((char*)h_hi + lb) = (u16)(pk & 0xFFFFu);
            *(u16*)((char*)h_lo + lb) = (u16)(pk >> 16);
        }
        __syncthreads();
    }
}

// ---------------------------------------------------------------------------
// HT -> h1/t1 hi/lo splits with ones column, zero-padded to KP
// ---------------------------------------------------------------------------
__global__ void split_ht(const float* __restrict__ HT, u16* __restrict__ h1h,
                         u16* __restrict__ h1l, u16* __restrict__ t1h,
                         u16* __restrict__ t1l)
{
    int idx = blockIdx.x * blockDim.x + threadIdx.x;
    if (idx >= 768 * KP) return;
    int m = idx / KP, k = idx - m * KP;
    float hv = (k < 512) ? HT[(size_t)m * 2048 + k] : (k == 512 ? 1.f : 0.f);
    float tv = (k < 512) ? HT[(size_t)m * 2048 + 512 + k] : (k == 512 ? 1.f : 0.f);
    u16 hh = f2bf(hv);
    h1h[idx] = hh; h1l[idx] = f2bf(hv - bf2f(hh));
    u16 th = f2bf(tv);
    t1h[idx] = th; t1l[idx] = f2bf(tv - bf2f(th));
}

// ---------------------------------------------------------------------------
// hv/tv (wave-parallel) + Tt tables; blocks 0..39 hv/tv, 40..41 Tt
// ---------------------------------------------------------------------------
__global__ __launch_bounds__(256)
void hvtv_ttab(const float* __restrict__ HT, const float* __restrict__ Wco,
               const float* __restrict__ size_emb,
               float* __restrict__ hv, float* __restrict__ tv, float* __restrict__ Tt)
{
    int bk = blockIdx.x;
    if (bk < 40) {
        int b = bk / 10, k = bk - (bk / 10) * 10;
        int wave = threadIdx.x >> 6, lane = threadIdx.x & 63;
        const float* wk = Wco + k * WCO_LD;
        for (int x = wave; x < 192; x += 4) {
            const float* hrow = HT + (size_t)(b * 192 + x) * 2048 + 1024;
            float sh = 0.f, st = 0.f;
            for (int i = lane; i < 512; i += 64) {
                sh = fmaf(hrow[i], wk[i], sh);
                st = fmaf(hrow[512 + i], wk[513 + i], st);
            }
#pragma unroll
            for (int o = 32; o; o >>= 1) {
                sh += __shfl_down(sh, o);
                st += __shfl_down(st, o);
            }
            if (lane == 0) {
                hv[bk * 192 + x] = sh + wk[512];
                tv[bk * 192 + x] = st + wk[1025];
            }
        }
    } else {
        int idx = (bk - 40) * 256 + threadIdx.x;
        if (idx < 300) {
            int k = idx / 30, p = idx - (idx / 30) * 30;
            float s = 0.f;
            for (int e = 0; e < 25; ++e)
                s = fmaf(size_emb[p * 25 + e], Wco[k * WCO_LD + 1026 + e], s);
            Tt[idx] = s;
        }
    }
}

extern "C" void kernel_launch(void* const* d_in, const int* in_sizes, int n_in,
                              void* d_out, int out_size, void* d_ws, size_t ws_size,
                              hipStream_t stream)
{
    const float* word_reps = (const float*)d_in[0];
    const int*   word_length = (const int*)d_in[1];
    const float* Wih_f = (const float*)d_in[4];
    const float* Whh_f = (const float*)d_in[5];
    const float* b_f   = (const float*)d_in[6];
    const float* Wih_b = (const float*)d_in[7];
    const float* Whh_b = (const float*)d_in[8];
    const float* b_b   = (const float*)d_in[9];
    const float* mlp1_w = (const float*)d_in[20];
    const float* mlp1_b = (const float*)d_in[21];
    const float* mlp2_w = (const float*)d_in[22];
    const float* mlp2_b = (const float*)d_in[23];
    const float* head_w = (const float*)d_in[24];
    const float* head_b = (const float*)d_in[25];
    const float* tail_w = (const float*)d_in[26];
    const float* tail_b = (const float*)d_in[27];
    const float* biaffW = (const float*)d_in[28];
    const float* size_emb = (const float*)d_in[29];
    const float* W_co = (const float*)d_in[30];

    float* W = (float*)d_ws;
    // region A (dead after mid GEMM; reused by Mbh = [0, 2088960) f32)
    float* xw   = W;                               // [0, 1572864)
    u16*  wrsh  = (u16*)(W + 1572864);             // [1572864, 1769472)
    u16*  wrsl  = (u16*)(W + 1769472);             // [1769472, 1966080)
    u16*  pw    = (u16*)(W + 1966080);             // [1966080, 2228224)
    u16*  Mbh   = (u16*)W;                         // 4,177,920 u16 -> [0, 2088960) f32
    // stable
    float* HT   = W + 2228224;                     // [2228224, 3801088)
    u16* h1h = (u16*)(W + 3801088);
    u16* h1l = (u16*)(W + 4009984);
    u16* t1h = (u16*)(W + 4218880);
    u16* t1l = (u16*)(W + 4427776);
    u16* Wsph = (u16*)(W + 4636672);               // [4636672, 6064128)
    u16* Wspl = (u16*)(W + 6064128);               // [6064128, 7491584)
    u16* Mbl  = (u16*)(W + 7491584);               // [7491584, 9580544)
    //   overlay of Mbl region (dead before biaff): wih split + bias_ih
    u16* wihh = (u16*)(W + 7491584);
    u16* wihl = (u16*)(W + 8278016);
    float* bias_ih = W + 9064448;                  // 2048
    float* hv = W + 9580544;
    float* tv = W + 9588224;
    float* Tt = W + 9595904;                       // 304
    u64* ex   = (u64*)(W + 9596208);               // 4096 u64
    u16* wrph = (u16*)(W + 9604400);               // 589,824 u16
    u16* wrpl = (u16*)(W + 9899312);
    u16* mwh  = (u16*)(W + 10194224);              // 1,048,576 u16
    u16* mwl  = (u16*)(W + 10718512);
    float* bias_mid = W + 11242800;                // 2048
    // high-water ~11,244,848 f32 = 45.0 MB

    // init: wr rows t >= L must be 0; ex stamps must not falsely match (1st call)
    hipMemsetAsync(wrsh, 0, (size_t)393216 * 2 * sizeof(u16), stream);
    hipMemsetAsync(ex, 0, (size_t)4096 * 8, stream);

    mega_prep<<<(3739648 + 255) / 256, 256, 0, stream>>>(
        word_reps, Wih_f, Wih_b, b_f, b_b,
        mlp1_w, mlp2_w, head_w, tail_w, mlp1_b, mlp2_b, head_b, tail_b,
        Whh_f, Whh_b,
        wrph, wrpl, wihh, wihl, bias_ih, mwh, mwl, bias_mid, pw);

    wsplit_kernel<<<dim3(17, 17, 10), dim3(32, 8), 0, stream>>>(biaffW, Wsph, Wspl);

    // xw = word_reps @ [Wih_f; Wih_b]^T + bias   (768 x 2048, one launch)
    gemm_mfma_hl<<<dim3(32, 12), 256, 0, stream>>>(wrph, wrpl, wihh, wihl, bias_ih, xw, 768, 2048, 0);

    // BiLSTM scan: r3 4-block protocol, weights truly register-resident
    lstm_mfma<<<4, 512, 0, stream>>>(xw, pw, word_length, wrsh, wrsl, ex);

    // HT = [gelu(wr@mlp1) | gelu(wr@mlp2) | leaky(wr@head) | leaky(wr@tail)]
    gemm_mfma_hl<<<dim3(32, 12), 256, 0, stream>>>(wrsh, wrsl, mwh, mwl, bias_mid, HT, 512, 2048, 3);

    split_ht<<<(768 * KP + 255) / 256, 256, 0, stream>>>(HT, h1h, h1l, t1h, t1l);
    hvtv_ttab<<<42, 256, 0, stream>>>(HT, W_co, size_emb, hv, tv, Tt);

    // Mb pad columns (j in [513,544)) must be ZERO: stale bytes as bf16 can be
    // NaN/Inf and NaN*0 = NaN in the final MFMA (round-5 lesson).
    hipMemsetAsync(Mbh, 0, (size_t)4177920 * 2, stream);
    hipMemsetAsync(Mbl, 0, (size_t)4177920 * 2, stream);

    biaff_mfma<<<dim3(41, 12), 256, 0, stream>>>(h1h, h1l, Wsph, Wspl, Mbh, Mbl);
    final_mfma<<<dim3(3, 120), 256, 0, stream>>>(Mbh, Mbl, t1h, t1l, hv, tv, Tt, (float*)d_out);
}